// Round 8
// baseline (107.437 us; speedup 1.0000x reference)
//
#include <hip/hip_runtime.h>

#define BATCH 8
#define NPTS 16384
#define MSKEL 1000
#define NCLS 100
#define CKK 10
#define MINDIS_INITF 100000.0f

// ws layout (16B aligned):
//   skelN  : float4[8000]   (-sx,-sy,-sz, 0.5|s|^2) per (b,m)
//   ptsM   : float4[131072] (x,y,z, 0.5|p|^2)       per (b,n)
//   minbits: uint[8000]     per-(b,m) min d^2 as uint bits
#define OFF_PTSM 32000
#define OFF_MINB (32000 + 524288)

// prep: build skelN and ptsM; init minbits to +inf; zero output accumulator.
__global__ __launch_bounds__(256) void k_prep(const float* __restrict__ xyz,
                                              const float* __restrict__ skel,
                                              float4* __restrict__ skelN,
                                              float4* __restrict__ ptsM,
                                              unsigned int* __restrict__ minbits,
                                              float* __restrict__ out) {
    const int gid = blockIdx.x * 256 + threadIdx.x;  // 131072 threads exactly
    {
        const float* p = xyz + (size_t)gid * 6;
        float x = p[0], y = p[1], z = p[2];
        ptsM[gid] = make_float4(x, y, z, 0.5f * (x * x + y * y + z * z));
    }
    if (gid < BATCH * MSKEL) {
        const float* s = skel + (size_t)gid * 3;
        float sx = s[0], sy = s[1], sz = s[2];
        skelN[gid] = make_float4(-sx, -sy, -sz, 0.5f * (sx * sx + sy * sy + sz * sz));
        minbits[gid] = 0x7F800000u;  // +inf
    }
    if (gid == 0) out[0] = 0.0f;
}

// Fused chamfer: 256 blocks x 512 threads (1 block/CU, 8 waves, 2 waves/SIMD).
//   blocks [0,128):   n-side — 1024-pt tile; each LANE owns 16 points, each of
//                     the 8 WAVES owns a 125-skel uniform slice → 64 VALU per
//                     s_load. 8-way cross-wave min via 32 KB LDS, block-sum,
//                     one atomicAdd into out (pre-scaled).
//   blocks [128,256): m-side — 1024-pt tile; 4 groups (2 waves each): each
//                     thread owns 8 skel in VGPRs (local*8), group streams a
//                     256-pt uniform slice → 32 VALU per s_load →
//                     atomicMin(minbits) per skel (64 contenders per slot).
__global__ __launch_bounds__(512, 2) void k_chamfer(const float4* __restrict__ skelN,
                                                    const float4* __restrict__ ptsM,
                                                    unsigned int* __restrict__ minbits,
                                                    float* __restrict__ out) {
    const int bid = blockIdx.x;
    const int tid = threadIdx.x;
    const int wave = tid >> 6, lane = tid & 63;

    if (bid < 128) {
        // ---------------- n-side ----------------
        const int b = bid >> 4, tile = bid & 15;
        const float4* __restrict__ base = ptsM + b * NPTS + tile * 1024;

        float4 P[16];
        float mt[16];
#pragma unroll
        for (int j = 0; j < 16; ++j) {
            P[j] = base[j * 64 + lane];  // coalesced dwordx4
            mt[j] = 3.4e38f;
        }

        const float4* __restrict__ sk = skelN + b * MSKEL + wave * 125;
#pragma unroll 5
        for (int m = 0; m < 125; ++m) {
            float4 s = sk[m];  // uniform -> scalar pipe; 64 VALU inst behind it
#pragma unroll
            for (int j = 0; j < 16; ++j) {
                float t = fmaf(P[j].x, s.x, fmaf(P[j].y, s.y, fmaf(P[j].z, s.z, s.w)));
                mt[j] = fminf(mt[j], t);
            }
        }

        // combine across the 8 wave-slices: sm[wave][pt] = mt + 0.5|p|^2
        __shared__ float sm[8 * 1024];  // 32 KB
#pragma unroll
        for (int j = 0; j < 16; ++j) {
            sm[wave * 1024 + j * 64 + lane] = mt[j] + P[j].w;
        }
        __syncthreads();

        // thread tid finalizes points tid and tid+512
        float a0 = sm[tid], a1 = sm[tid + 512];
#pragma unroll
        for (int w = 1; w < 8; ++w) {
            a0 = fminf(a0, sm[w * 1024 + tid]);
            a1 = fminf(a1, sm[w * 1024 + tid + 512]);
        }
        float d = sqrtf(fmaxf(2.0f * a0, 1e-12f)) + sqrtf(fmaxf(2.0f * a1, 1e-12f));

#pragma unroll
        for (int o = 32; o > 0; o >>= 1) d += __shfl_down(d, o, 64);
        __shared__ float s_part[8];
        if (lane == 0) s_part[wave] = d;
        __syncthreads();
        if (tid == 0) {
            float sum = 0.0f;
#pragma unroll
            for (int w = 0; w < 8; ++w) sum += s_part[w];
            atomicAdd(out, 0.0125f * sum);  // 0.1 / BATCH
        }
    } else {
        // ---------------- m-side ----------------
        const int id = bid - 128;
        const int b = id >> 4, tile = id & 15;
        const int group = tid >> 7;           // 0..3, uniform per wave
        const int local = tid & 127;          // skel owner index within group
        const int m0 = local * 8;             // 8 consecutive skel per thread

        float4 S[8];
        float mind[8];
#pragma unroll
        for (int k = 0; k < 8; ++k) {
            const int m = m0 + k;
            S[k] = (m < MSKEL) ? skelN[b * MSKEL + m]
                               : make_float4(0.0f, 0.0f, 0.0f, 0.0f);
            mind[k] = 3.4e38f;
        }

        const float4* __restrict__ pp = ptsM + b * NPTS + tile * 1024 + group * 256;
#pragma unroll 8
        for (int n = 0; n < 256; ++n) {
            float4 r = pp[n];  // uniform -> scalar pipe; 32 VALU inst behind it
#pragma unroll
            for (int k = 0; k < 8; ++k) {
                // t = 0.5|p|^2 - p.s ; d^2 = 2(t + 0.5|s|^2)
                float t = fmaf(r.x, S[k].x, fmaf(r.y, S[k].y, fmaf(r.z, S[k].z, r.w)));
                mind[k] = fminf(mind[k], t);
            }
        }
#pragma unroll
        for (int k = 0; k < 8; ++k) {
            const int m = m0 + k;
            if (m < MSKEL) {
                float d2 = 2.0f * (mind[k] + S[k].w);
                // clamp fp-cancellation negatives so uint order == float order
                atomicMin(&minbits[b * MSKEL + m], __float_as_uint(fmaxf(d2, 0.0f)));
            }
        }
    }
}

// reduce: m-side mins (32 KB) + convex-hull term; atomicAdd into out.
__global__ __launch_bounds__(256) void k_reduce(const float* __restrict__ skel,
                                                const int* __restrict__ labels,
                                                const unsigned int* __restrict__ minbits,
                                                float* __restrict__ out) {
    const int gid = blockIdx.x * 256 + threadIdx.x;  // 8 blocks = 2048 threads
    const int tid = threadIdx.x;
    float acc = 0.0f;

    for (int i = gid; i < BATCH * MSKEL; i += 2048) {
        acc += 0.0125f * sqrtf(fmaxf(__uint_as_float(minbits[i]), 1e-12f));
    }

    if (gid < BATCH * NCLS) {
        const int b = gid / NCLS, c = gid - b * NCLS;
        const float* cp = skel + ((size_t)b * MSKEL + c * CKK) * 3;
        const int* lab = labels + (size_t)b * NCLS * CKK + c * CKK;
        float x[CKK], y[CKK], z[CKK];
        int lv[CKK];
#pragma unroll
        for (int i = 0; i < CKK; ++i) {
            x[i] = cp[i * 3 + 0]; y[i] = cp[i * 3 + 1]; z[i] = cp[i * 3 + 2];
            lv[i] = lab[i];
        }
        float convexSum = 0.0f;
#pragma unroll
        for (int i = 0; i < CKK; ++i) {
            if (lv[i] != 1) {
                float mind = MINDIS_INITF;
#pragma unroll
                for (int j = 0; j < CKK; ++j) {
                    if (lv[j] == 1) {
                        float dx = x[i] - x[j], dy = y[i] - y[j], dz = z[i] - z[j];
                        mind = fminf(mind, dx * dx + dy * dy + dz * dz);
                    }
                }
                convexSum += mind;
            }
        }
        acc += convexSum * (1.0f / (BATCH * NCLS));
    }

#pragma unroll
    for (int o = 32; o > 0; o >>= 1) acc += __shfl_down(acc, o, 64);
    __shared__ float s_part[4];
    const int wave = tid >> 6, lane = tid & 63;
    if (lane == 0) s_part[wave] = acc;
    __syncthreads();
    if (tid == 0) {
        atomicAdd(out, s_part[0] + s_part[1] + s_part[2] + s_part[3]);
    }
}

extern "C" void kernel_launch(void* const* d_in, const int* in_sizes, int n_in,
                              void* d_out, int out_size, void* d_ws, size_t ws_size,
                              hipStream_t stream) {
    const float* xyz = (const float*)d_in[0];
    const float* skel = (const float*)d_in[1];
    // d_in[2] = weights (unused by reference)
    const int* labels = (const int*)d_in[3];
    float* out = (float*)d_out;

    float4* skelN = (float4*)d_ws;
    float4* ptsM = (float4*)((float*)d_ws + OFF_PTSM);
    unsigned int* minbits = (unsigned int*)((float*)d_ws + OFF_MINB);

    k_prep<<<512, 256, 0, stream>>>(xyz, skel, skelN, ptsM, minbits, out);
    k_chamfer<<<256, 512, 0, stream>>>(skelN, ptsM, minbits, out);
    k_reduce<<<8, 256, 0, stream>>>(skel, labels, minbits, out);
}